// Round 7
// baseline (848.119 us; speedup 1.0000x reference)
//
#include <hip/hip_runtime.h>
#include <math.h>

#define VOCAB 50000
#define EE 301
#define DD 25
#define SEQ 128
#define NC 5
#define NCOL 650   // 625 x@A columns + 25 x@W columns
#define BROW 656   // Bmat row stride (floats)
#define TROW 704   // T row stride (floats): i-run at i*28 (16B-aligned), q at i*28+25

// ---------------- Bmat[e][c]: exact copies, NO folding ----------------
// c<625: A[i=c/25][e][d=c%25]; 625<=c<650: W[e][c-625]; else 0
__global__ __launch_bounds__(256) void build_B(
    const float* __restrict__ A, const float* __restrict__ W,
    float* __restrict__ Bmat)
{
    int e = blockIdx.x;
    for (int c = threadIdx.x; c < BROW; c += 256) {
        float v = 0.f;
        if (c < 625) {
            int i = c / 25, d = c % 25;
            v = A[((size_t)i * EE + e) * DD + d];
        } else if (c < NCOL) {
            v = W[(size_t)e * DD + (c - 625)];
        }
        Bmat[(size_t)e * BROW + c] = v;
    }
}

// ---------------- T = emb @ Bmat (ascending-k fmaf chain per element) ----------------
// 128x128 tile, 256 threads, 8x8 microtile. Output stored in scan-friendly layout:
// col n<625 -> (n/25)*28 + n%25 ; col 625+i -> i*28+25.
__global__ __launch_bounds__(256) void gemm_T(
    const float* __restrict__ emb,   // [VOCAB][301]
    const float* __restrict__ Bmat,  // [301][BROW]
    float* __restrict__ T)           // [VOCAB][TROW]
{
    __shared__ float As[16][132];    // 128m x 16k, stride 132 (16B-aligned frags, 2-way-max conflicts)
    __shared__ float Bs[16][128];
    int tid = threadIdx.x;
    int tx = tid & 15, ty = tid >> 4;
    int m0 = blockIdx.x * 128, n0 = blockIdx.y * 128;

    float acc[8][8];
#pragma unroll
    for (int a = 0; a < 8; ++a)
#pragma unroll
        for (int c = 0; c < 8; ++c) acc[a][c] = 0.f;

    // store-column mapping (scan layout), precomputed
    int  coff[8];
    bool cval[8];
#pragma unroll
    for (int c = 0; c < 8; ++c) {
        int n = n0 + tx * 8 + c;
        cval[c] = (n < NCOL);
        int nn = cval[c] ? n : 0;
        coff[c] = (nn < 625) ? (nn / 25) * 28 + (nn % 25) : (nn - 625) * 28 + 25;
    }

    for (int k0 = 0; k0 < EE; k0 += 16) {
#pragma unroll
        for (int p = 0; p < 8; ++p) {          // As: k-contig global reads
            int idx = tid + p * 256;
            int kl = idx & 15, ml = idx >> 4;
            int m = m0 + ml, k = k0 + kl;
            As[kl][ml] = (m < VOCAB && k < EE) ? emb[(size_t)m * EE + k] : 0.f;
        }
#pragma unroll
        for (int p = 0; p < 8; ++p) {          // Bs: n-contig global reads
            int idx = tid + p * 256;
            int nl = idx & 127, kl = idx >> 7;
            int k = k0 + kl, n = n0 + nl;
            Bs[kl][nl] = (k < EE && n < NCOL) ? Bmat[(size_t)k * BROW + n] : 0.f;
        }
        __syncthreads();
#pragma unroll
        for (int kk = 0; kk < 16; ++kk) {      // global k strictly ascending
            float4 a0 = *(const float4*)&As[kk][ty * 8];
            float4 a1 = *(const float4*)&As[kk][ty * 8 + 4];
            float4 b0 = *(const float4*)&Bs[kk][tx * 8];
            float4 b1 = *(const float4*)&Bs[kk][tx * 8 + 4];
            float av[8] = {a0.x, a0.y, a0.z, a0.w, a1.x, a1.y, a1.z, a1.w};
            float bv[8] = {b0.x, b0.y, b0.z, b0.w, b1.x, b1.y, b1.z, b1.w};
#pragma unroll
            for (int a = 0; a < 8; ++a)
#pragma unroll
                for (int c = 0; c < 8; ++c)
                    acc[a][c] = fmaf(av[a], bv[c], acc[a][c]);
        }
        __syncthreads();
    }
#pragma unroll
    for (int a = 0; a < 8; ++a) {
        int m = m0 + ty * 8 + a;
        if (m < VOCAB) {
            float* row = T + (size_t)m * TROW;
#pragma unroll
            for (int c = 0; c < 8; ++c)
                if (cval[c]) row[coff[c]] = acc[a][c];
        }
    }
}

// ---------------- scan: frozen R6 numerics, prefetched + shuffle-based ----------------
// a[b,i]: (b%4==0 && i%4==0) -> SSE 4-partial association + scalar tail;
// else strict ascending scalar chain (mul+add, no fma).
// lin = ((x@W)+(h@V))+b ; pre = a+lin ; h = fp32(tanh_f64(pre)).
__global__ __launch_bounds__(256) void rnn_scan_np4(
    const int*   __restrict__ words,  // [B][SEQ]
    const float* __restrict__ T,      // [VOCAB][TROW]
    const float* __restrict__ V,      // [DD][DD]
    const float* __restrict__ bvec,   // [DD]
    const float* __restrict__ outW,   // [NC][DD]
    const float* __restrict__ outB,   // [NC]
    float* __restrict__ out,          // [B][NC]
    int B)
{
    int tid = threadIdx.x;
    int g = tid >> 5, i = tid & 31;
    int b = blockIdx.x * 8 + g;
    bool act = (i < DD) && (b < B);
    int ii = (i < DD) ? i : (DD - 1);
    int bsafe = (b < B) ? b : 0;
    const int* wr = words + (size_t)bsafe * SEQ;

    float Vcol[DD];
#pragma unroll
    for (int j = 0; j < DD; ++j) Vcol[j] = V[j * DD + ii];   // h@V contracts V[j,i]
    float bi = bvec[ii];

    float hr[DD];
#pragma unroll
    for (int j = 0; j < DD; ++j) hr[j] = 0.f;
    hr[DD - 1] = 1.f;                                        // h0 = e_24

    bool sse = ((b & 3) == 0) && ((i & 3) == 0);
    const float* base = T + (size_t)ii * 28;

    float4 cur[7], nxt[7];
    {
        const float* R = base + (size_t)wr[0] * TROW;
#pragma unroll
        for (int u = 0; u < 7; ++u) cur[u] = *(const float4*)(R + u * 4);
    }

    float hnew = 0.f;
    for (int t = 0; t < SEQ; ++t) {
        // prefetch row t+1 (word-indexed, independent of h) while computing step t
        int wn = wr[(t + 1 < SEQ) ? t + 1 : t];
        const float* Rn = base + (size_t)wn * TROW;
#pragma unroll
        for (int u = 0; u < 7; ++u) nxt[u] = *(const float4*)(Rn + u * 4);

        float Tj[28];
#pragma unroll
        for (int u = 0; u < 7; ++u) {
            Tj[u * 4 + 0] = cur[u].x; Tj[u * 4 + 1] = cur[u].y;
            Tj[u * 4 + 2] = cur[u].z; Tj[u * 4 + 3] = cur[u].w;
        }
        float qv = Tj[25];

        float a;
        if (sse) {
            float p0 = 0.f, p1 = 0.f, p2 = 0.f, p3 = 0.f;
#pragma unroll
            for (int j = 0; j < 24; j += 4) {
                p0 = __fadd_rn(p0, __fmul_rn(Tj[j],     hr[j]));
                p1 = __fadd_rn(p1, __fmul_rn(Tj[j + 1], hr[j + 1]));
                p2 = __fadd_rn(p2, __fmul_rn(Tj[j + 2], hr[j + 2]));
                p3 = __fadd_rn(p3, __fmul_rn(Tj[j + 3], hr[j + 3]));
            }
            float s02 = __fadd_rn(p0, p2);
            float s13 = __fadd_rn(p1, p3);
            a = __fadd_rn(s02, s13);
            a = __fadd_rn(a, __fmul_rn(Tj[24], hr[24]));     // scalar tail j=24
        } else {
            a = 0.f;
#pragma unroll
            for (int j = 0; j < DD; ++j)
                a = __fadd_rn(a, __fmul_rn(Tj[j], hr[j]));
        }

        float r2 = 0.f;                                      // h@V: BLAS k-seq FMA
#pragma unroll
        for (int j = 0; j < DD; ++j)
            r2 = fmaf(hr[j], Vcol[j], r2);

        float lin = __fadd_rn(__fadd_rn(qv, r2), bi);        // (xW + hV) + b
        float pre = __fadd_rn(a, lin);                       // a + lin
        hnew = act ? (float)tanh((double)pre) : 0.f;

#pragma unroll
        for (int j = 0; j < DD; ++j)                          // broadcast h within 32-group
            hr[j] = __shfl(hnew, j, 32);

#pragma unroll
        for (int u = 0; u < 7; ++u) cur[u] = nxt[u];
    }

    // logits = h @ out_W.T + out_b ; sigmoid  (BLAS k-seq FMA)
    if (i < NC && b < B) {
        float acc = 0.f;
#pragma unroll
        for (int j = 0; j < DD; ++j)
            acc = fmaf(hr[j], outW[i * DD + j], acc);
        float l = __fadd_rn(acc, outB[i]);
        out[(size_t)b * NC + i] = (float)(1.0 / (1.0 + exp(-(double)l)));
    }
}

extern "C" void kernel_launch(void* const* d_in, const int* in_sizes, int n_in,
                              void* d_out, int out_size, void* d_ws, size_t ws_size,
                              hipStream_t stream)
{
    const int*   words = (const int*)d_in[0];
    const float* emb   = (const float*)d_in[2];
    const float* A     = (const float*)d_in[3];
    const float* W     = (const float*)d_in[4];
    const float* V     = (const float*)d_in[5];
    const float* bias  = (const float*)d_in[6];
    const float* outW  = (const float*)d_in[7];
    const float* outB  = (const float*)d_in[8];
    float* out = (float*)d_out;
    int B = in_sizes[0] / SEQ;

    float* Bmat = (float*)d_ws;                        // 301*656*4 ≈ 0.79 MB
    float* T    = (float*)((char*)d_ws + (1 << 20));   // 50000*704*4 ≈ 140.8 MB

    build_B<<<EE, 256, 0, stream>>>(A, W, Bmat);
    gemm_T<<<dim3((VOCAB + 127) / 128, (NCOL + 127) / 128), 256, 0, stream>>>(emb, Bmat, T);
    rnn_scan_np4<<<(B + 7) / 8, 256, 0, stream>>>(words, T, V, bias, outW, outB, out, B);
}